// Round 7
// baseline (484.498 us; speedup 1.0000x reference)
//
#include <hip/hip_runtime.h>
#include <hip/hip_bf16.h>

typedef __bf16 bf16;
typedef __attribute__((ext_vector_type(8)))  __bf16 bf16x8;
typedef __attribute__((ext_vector_type(4)))  __bf16 bf16x4;
typedef __attribute__((ext_vector_type(4)))  float  f32x4;

#define SEQ   2048
#define NDIM  256
#define NH3   48
#define CH    64
#define SQS   72     // sQ row stride (pad: rows advance 4 banks)
#define SVS   72     // sV row stride
#define SPS   72     // sP row stride (R14 proved 64+XOR cuts conflicts but costs +38us)
#define VTS   2176   // g_vt row stride (4352B = 17 x 256B sectors)

// canonical bf16 input arena offsets (elements; multiples of 8 -> 16B aligned)
#define OFF_NODES 0
#define OFF_POS   524288
#define OFF_ROT   536576
#define OFF_WN    544768
#define OFF_BN    1069056
#define OFF_WP    1071104
#define OFF_BP    1083392
#define OFF_WR    1085440
#define OFF_WV    1093632
#define OFF_BV    4239360
#define TOT_IN    4251648

__device__ bf16  g_in[TOT_IN];              // 8.5 MB canonical bf16 inputs
__device__ bf16  g_k [NH3 * SEQ * CH];      // [h][s][c] 12.6 MB
__device__ bf16  g_q [NH3 * SEQ * CH];      // [h][s][c] 12.6 MB
__device__ bf16  g_vt[NH3 * NDIM * VTS];    // [h][d][j'] padded, j-permuted per 64-block
__device__ float g_part[(size_t)NH3 * SEQ * NDIM];  // 100 MB per-head partials (no atomics)
__device__ int   g_isf32;

// ---------------------------------------------------------------- dtype probe
__global__ __launch_bounds__(256) void detect_k(const unsigned short* __restrict__ p) {
    __shared__ int cff, czero;
    if (threadIdx.x == 0) { cff = 0; czero = 0; }
    __syncthreads();
    int ff = 0, zz = 0;
    for (int r = 0; r < 64; ++r) {
        int idx = threadIdx.x * 64 + r;
        unsigned short u = p[idx];
        if (((u >> 7) & 0xFF) == 0xFF) ff++;
        if (((idx & 1) == 0) && (u == 0)) zz++;
    }
    if (ff) atomicAdd(&cff, ff);
    if (zz) atomicAdd(&czero, zz);
    __syncthreads();
    if (threadIdx.x == 0) g_isf32 = (cff > 2 || czero > 6000) ? 1 : 0;
}

// --------------------------------------------------------- input canonicalize
__global__ __launch_bounds__(256) void convert_k(
    const void* s0, const void* s1, const void* s2, const void* s3, const void* s4,
    const void* s5, const void* s6, const void* s7, const void* s8, const void* s9)
{
    const void* srcs[10] = {s0, s1, s2, s3, s4, s5, s6, s7, s8, s9};
    const int   szs[10]  = {524288, 12288, 8192, 524288, 2048, 12288, 2048, 8192, 3145728, 12288};
    const int   offs[10] = {OFF_NODES, OFF_POS, OFF_ROT, OFF_WN, OFF_BN,
                            OFF_WP, OFF_BP, OFF_WR, OFF_WV, OFF_BV};
    const int y = blockIdx.y;
    const void* src = srcs[y];
    bf16* dst = g_in + offs[y];
    const int n = szs[y];
    const int isf = g_isf32;
    const int stride = gridDim.x * 256 * 4;
    for (int i = (blockIdx.x * 256 + threadIdx.x) * 4; i < n; i += stride) {
        bf16x4 o;
        if (isf) {
            float4 v = *(const float4*)((const float*)src + i);
            o[0] = (bf16)v.x; o[1] = (bf16)v.y; o[2] = (bf16)v.z; o[3] = (bf16)v.w;
        } else {
            o = *(const bf16x4*)((const bf16*)src + i);
        }
        *(bf16x4*)(dst + i) = o;
    }
}

// ------------------------------------------------- fused projections (1 launch)
// blocks [0,1024)      : nodes -> k,q heads 0-15   (XCD-swizzled)
// blocks [1024,9216)   : pos/rot -> k,q heads 16-47
// blocks [9216,15360)  : nodes -> V (transposed+permuted), XCD-swizzled
__global__ __launch_bounds__(256) void proj_all()
{
    __shared__ __align__(16) bf16 sB[64 * 264];
    __shared__ __align__(16) bf16 sO[64 * 72];
    const int t  = threadIdx.x;
    const int gb = blockIdx.x;

    if (gb < 1024) {
        // ---------------- nodes -> k,q (heads 0-15)
        const bf16* nodes = g_in + OFF_NODES;
        const bf16* Wn    = g_in + OFF_WN;
        const bf16* bn    = g_in + OFF_BN;
        const int bx   = gb;
        const int xcd  = bx & 7;
        const int rest = bx >> 3;             // 0..127
        const int f0   = (xcd * 4 + (rest & 3)) * 64;   // 4 f-blocks per XCD
        const int s0   = (rest >> 2) * 64;              // 0..31

        for (int rep = 0; rep < 8; ++rep) {
            int idx = t + rep * 256;
            int row = idx >> 5, chunk = idx & 31;
            *(bf16x8*)&sB[row * 264 + chunk * 8] =
                *(const bf16x8*)&Wn[(f0 + row) * 256 + chunk * 8];
        }
        __syncthreads();

        const int w = t >> 6, lane = t & 63;
        const int l15 = lane & 15, quad = lane >> 4;

        f32x4 acc[4] = {{}, {}, {}, {}};
        const bf16* arow = nodes + (s0 + w * 16 + l15) * 256 + quad * 8;
#pragma unroll
        for (int kc = 0; kc < 8; ++kc) {
            bf16x8 af = *(const bf16x8*)(arow + kc * 32);
#pragma unroll
            for (int ft = 0; ft < 4; ++ft) {
                bf16x8 bfr = *(const bf16x8*)&sB[(ft * 16 + l15) * 264 + kc * 32 + quad * 8];
                acc[ft] = __builtin_amdgcn_mfma_f32_16x16x32_bf16(af, bfr, acc[ft], 0, 0, 0);
            }
        }
#pragma unroll
        for (int ft = 0; ft < 4; ++ft) {
            int f = f0 + ft * 16 + l15;
            float bias = (float)bn[f];
            int h = f >> 7, c2 = f & 127;
            bf16* base = (c2 < 64) ? (g_k + h * SEQ * CH + c2)
                                   : (g_q + h * SEQ * CH + (c2 - 64));
#pragma unroll
            for (int r = 0; r < 4; ++r) {
                int s = s0 + w * 16 + quad * 4 + r;
                base[s * CH] = (bf16)(acc[ft][r] + bias);
            }
        }
    } else if (gb < 9216) {
        // ---------------- pos/rot -> k,q (heads 16-31 / 32-47)
        const bf16* pos  = g_in + OFF_POS;
        const bf16* rotq = g_in + OFF_ROT;
        const bf16* Wp   = g_in + OFF_WP;
        const bf16* bp   = g_in + OFF_BP;
        const bf16* Wr   = g_in + OFF_WR;
        int id = (gb - 1024) * 256 + t;           // 2 * 2048 * 512
        int fg  = id & 511;                        // f-group of 4
        int s   = (id >> 9) & 2047;
        int src = id >> 20;
        int f0  = fg * 4;
        float y[4]; int h;
        if (src == 0) {
#pragma unroll
            for (int j = 0; j < 4; ++j) {
                float a = (float)bp[f0 + j];
#pragma unroll
                for (int x = 0; x < 6; ++x)
                    a += (float)pos[s * 6 + x] * (float)Wp[(f0 + j) * 6 + x];
                y[j] = a;
            }
            h = 16 + (f0 >> 7);
        } else {
#pragma unroll
            for (int j = 0; j < 4; ++j) {
                float a = 0.f;
#pragma unroll
                for (int x = 0; x < 4; ++x)
                    a += (float)rotq[s * 4 + x] * (float)Wr[(f0 + j) * 4 + x];
                y[j] = a;
            }
            h = 32 + (f0 >> 7);
        }
        bf16x4 o;
#pragma unroll
        for (int j = 0; j < 4; ++j) o[j] = (bf16)y[j];
        int c2 = f0 & 127;
        if (c2 < 64) *(bf16x4*)&g_k[(h * SEQ + s) * CH + c2]        = o;
        else         *(bf16x4*)&g_q[(h * SEQ + s) * CH + (c2 - 64)] = o;
    } else {
        // ---------------- nodes -> V (transposed + j-permuted, padded stride)
        const bf16* nodes = g_in + OFF_NODES;
        const bf16* Wv    = g_in + OFF_WV;
        const bf16* bv    = g_in + OFF_BV;
        const int bx   = gb - 9216;           // 0..6143
        const int xcd  = bx & 7;
        const int rest = bx >> 3;             // 0..767
        const int f0   = (xcd * 24 + (rest % 24)) * 64;  // 24 f-blocks per XCD
        const int s0   = (rest / 24) * 64;               // 0..31

        for (int rep = 0; rep < 8; ++rep) {
            int idx = t + rep * 256;
            int row = idx >> 5, chunk = idx & 31;
            *(bf16x8*)&sB[row * 264 + chunk * 8] =
                *(const bf16x8*)&Wv[(size_t)(f0 + row) * 256 + chunk * 8];
        }
        __syncthreads();

        const int w = t >> 6, lane = t & 63;
        const int l15 = lane & 15, quad = lane >> 4;

        f32x4 acc[4] = {{}, {}, {}, {}};
        const bf16* arow = nodes + (s0 + w * 16 + l15) * 256 + quad * 8;
#pragma unroll
        for (int kc = 0; kc < 8; ++kc) {
            bf16x8 af = *(const bf16x8*)(arow + kc * 32);
#pragma unroll
            for (int ft = 0; ft < 4; ++ft) {
                bf16x8 bfr = *(const bf16x8*)&sB[(ft * 16 + l15) * 264 + kc * 32 + quad * 8];
                acc[ft] = __builtin_amdgcn_mfma_f32_16x16x32_bf16(af, bfr, acc[ft], 0, 0, 0);
            }
        }
        __syncthreads();
#pragma unroll
        for (int ft = 0; ft < 4; ++ft) {
            int n = f0 + ft * 16 + l15;
            float bias = (float)bv[n];
#pragma unroll
            for (int r = 0; r < 4; ++r) {
                // s-local l = w*16+quad*4+r -> j' = (quad*4+r)*4 + w
                sO[(ft * 16 + l15) * 72 + (quad * 4 + r) * 4 + w] = (bf16)(acc[ft][r] + bias);
            }
        }
        __syncthreads();
        for (int rep = 0; rep < 2; ++rep) {
            int idx = t + rep * 256;
            int row = idx >> 3, chunk = idx & 7;
            *(bf16x8*)&g_vt[(size_t)(f0 + row) * VTS + s0 + chunk * 8] =
                *(const bf16x8*)&sO[row * 72 + chunk * 8];
        }
    }
}

// ------------------------------------------------------------- attention
// R18 = R11 with T14 issue-early + counted-vmcnt-across-barrier:
//  - next-step staging loads issued at TOP of the step (right after B1 freed
//    qpre/vpre via its lgkmcnt drain) instead of post-B2 -> the HBM straggler
//    (~3.3KB/block-step always misses to HBM, ~900cy) gets S+P+PV (~700-1000cy)
//    of cover instead of only PV (~300-600cy).
//  - B2 and B3 become lgkmcnt(0)-only raw barriers so the in-flight loads are
//    NOT drained at the barrier (T4). LDS ordering (write-before-barrier vs
//    read-after-barrier) is fully lgkm-tracked; the post-B3 ds_writes' data
//    dependence on the loads gets compiler-inserted counted vmcnt.
//  - B1 stays __syncthreads (no vmem outstanding there; free drain).
// Registers unchanged (same qpre/vpre, earlier issue). Watch VGPR_Count:
// >64 would drop occupancy 16->12 waves/CU (the failure mode).
// Failed grafts (keep away): sV-from-global (R12), s_setprio (R13: breaks
// inter-block lockstep L2 reuse, FETCH 4x), sP 64+XOR (R14: +38us),
// work stealing (R16: quantization + atomic cost).
__global__ __launch_bounds__(512, 4) void attn_k()
{
    const int bx  = blockIdx.x;
    const int xcd = bx & 7;
    const int sub = bx >> 3;             // 0..95
    const int h   = xcd * 6 + (sub % 6); // 6 heads per XCD
    const int it  = sub / 6;             // 0..15
    const int i0  = it * 128;
    const int t   = threadIdx.x;
    const int w   = t >> 6, lane = t & 63;
    const int l15 = lane & 15, quad = lane >> 4;
    const bool rot = (h >= 32);

    __shared__ __align__(16) bf16 sQ[64 * SQS];      //  9216 B
    __shared__ __align__(16) bf16 sV[256 * SVS];     // 36864 B
    __shared__ __align__(16) bf16 sP[128 * SPS];     // 18432 B
    __shared__ float sL[128];                        //   512 B (total 65024)

    const bf16* kb = g_k  + h * SEQ * CH;
    const bf16* qb = g_q  + h * SEQ * CH;
    const bf16* vb = g_vt + (size_t)h * NDIM * VTS;

    // K fragments: wave w owns S-rows i0 + w*16 .. +16
    bf16x8 kf0 = *(const bf16x8*)&kb[(i0 + w * 16 + l15) * CH + quad * 8];
    bf16x8 kf1 = *(const bf16x8*)&kb[(i0 + w * 16 + l15) * CH + 32 + quad * 8];

    // PV split: i-half ih = w>>2 (64 rows), d-quarter dq = w&3 (64 cols)
    const int ih = w >> 2, dq = w & 3;

    // staging decomposition (16B chunks)
    const int qrow = t >> 3, qch = t & 7;

    f32x4 acc[4][4];
#pragma unroll
    for (int a = 0; a < 4; ++a)
#pragma unroll
        for (int b = 0; b < 4; ++b) acc[a][b] = (f32x4){0.f, 0.f, 0.f, 0.f};
    f32x4 lp = {0.f, 0.f, 0.f, 0.f};

    // prefetch step 0 into regs
    bf16x8 qpre, vpre[4];
    qpre = *(const bf16x8*)&qb[t * 8];
#pragma unroll
    for (int rep = 0; rep < 4; ++rep) {
        int idx = t + rep * 512;
        vpre[rep] = *(const bf16x8*)&vb[(size_t)(idx >> 3) * VTS + (idx & 7) * 8];
    }
    // write step 0 to LDS
    *(bf16x8*)&sQ[qrow * SQS + qch * 8] = qpre;
#pragma unroll
    for (int rep = 0; rep < 4; ++rep) {
        int idx = t + rep * 512;
        *(bf16x8*)&sV[(idx >> 3) * SVS + (idx & 7) * 8] = vpre[rep];
    }
    __syncthreads();                                   // B1 (step 0)

    for (int st = 0; st < 32; ++st) {
        // ---- issue next step's global loads FIRST (T14 issue-early).
        // B1 of the previous iteration drained lgkmcnt -> the staged ds_writes
        // are complete and qpre/vpre are free to be load destinations again.
        if (st < 31) {
            const bf16* qn = qb + (st + 1) * 4096;
            const bf16* vn = vb + (st + 1) * 64;
            qpre = *(const bf16x8*)&qn[t * 8];
#pragma unroll
            for (int rep = 0; rep < 4; ++rep) {
                int idx = t + rep * 512;
                vpre[rep] = *(const bf16x8*)&vn[(size_t)(idx >> 3) * VTS + (idx & 7) * 8];
            }
        }

        // ---- S phase: 16 i-rows x 64 j per wave
        f32x4 sjb[4];
#pragma unroll
        for (int jb = 0; jb < 4; ++jb) {
            bf16x8 q0 = *(const bf16x8*)&sQ[(jb * 16 + l15) * SQS + quad * 8];
            bf16x8 q1 = *(const bf16x8*)&sQ[(jb * 16 + l15) * SQS + 32 + quad * 8];
            f32x4 sa = {};
            sa = __builtin_amdgcn_mfma_f32_16x16x32_bf16(kf0, q0, sa, 0, 0, 0);
            sa = __builtin_amdgcn_mfma_f32_16x16x32_bf16(kf1, q1, sa, 0, 0, 0);
            sjb[jb] = sa;
        }

        // ---- P phase: exp + pack; column j' = l15*4 + jb (logical j = jb*16+l15)
#pragma unroll
        for (int r = 0; r < 4; ++r) {
            bf16x4 pk;
#pragma unroll
            for (int jb = 0; jb < 4; ++jb) {
                float d = sjb[jb][r];
                float x = rot ? (d * d * 0.25f) : (d * 0.25f);
                x = fminf(x, 60.f);
                float p = __expf(x);
                lp[r] += p;
                pk[jb] = (bf16)p;
            }
            *(bf16x4*)&sP[(w * 16 + quad * 4 + r) * SPS + l15 * 4] = pk;
        }

        // ---- B2 (weak): sP visible; do NOT drain vmcnt (loads stay in flight)
        asm volatile("s_waitcnt lgkmcnt(0)" ::: "memory");
        __builtin_amdgcn_s_barrier();

        // ---- PV phase: wave w owns (ih, dq): 64 i x 64 d
#pragma unroll
        for (int kc = 0; kc < 2; ++kc) {
            bf16x8 ap[4], vf[4];
#pragma unroll
            for (int itr = 0; itr < 4; ++itr)
                ap[itr] = *(const bf16x8*)&sP[(ih * 64 + itr * 16 + l15) * SPS + kc * 32 + quad * 8];
#pragma unroll
            for (int dt = 0; dt < 4; ++dt)
                vf[dt] = *(const bf16x8*)&sV[(dq * 64 + dt * 16 + l15) * SVS + kc * 32 + quad * 8];
#pragma unroll
            for (int itr = 0; itr < 4; ++itr)
#pragma unroll
                for (int dt = 0; dt < 4; ++dt)
                    acc[itr][dt] = __builtin_amdgcn_mfma_f32_16x16x32_bf16(
                        ap[itr], vf[dt], acc[itr][dt], 0, 0, 0);
        }

        // ---- B3 (weak): all LDS reads done; loads may still be in flight
        asm volatile("s_waitcnt lgkmcnt(0)" ::: "memory");
        __builtin_amdgcn_s_barrier();

        // ---- write staged regs for next step (compiler inserts counted vmcnt
        //      for the qpre/vpre data dependence — per-wave, not all-wave)
        if (st < 31) {
            *(bf16x8*)&sQ[qrow * SQS + qch * 8] = qpre;
#pragma unroll
            for (int rep = 0; rep < 4; ++rep) {
                int idx = t + rep * 512;
                *(bf16x8*)&sV[(idx >> 3) * SVS + (idx & 7) * 8] = vpre[rep];
            }
            __syncthreads();                           // B1 (full): staging visible
        }
    }

    // l reduce across the 16 j-lanes (wave w owns S-rows w*16..+16)
#pragma unroll
    for (int off = 1; off < 16; off <<= 1) {
#pragma unroll
        for (int r = 0; r < 4; ++r) lp[r] += __shfl_xor(lp[r], off, 64);
    }
    if (l15 == 0) *(f32x4*)&sL[w * 16 + quad * 4] = lp;
    __syncthreads();

    // normalize + plain stores into this head's private partial plane
    float* pb = g_part + (size_t)h * SEQ * NDIM;
#pragma unroll
    for (int itr = 0; itr < 4; ++itr) {
        f32x4 lv = *(const f32x4*)&sL[ih * 64 + itr * 16 + quad * 4];
#pragma unroll
        for (int r = 0; r < 4; ++r) {
            float inv = 1.0f / lv[r];
            float* ob = &pb[(size_t)(i0 + ih * 64 + itr * 16 + quad * 4 + r) * NDIM + dq * 64 + l15];
#pragma unroll
            for (int dt = 0; dt < 4; ++dt)
                ob[dt * 16] = acc[itr][dt][r] * inv;
        }
    }
}

// ------------------------------------------- finalize: sum 48 head planes
__global__ __launch_bounds__(256) void finalize_k(float* __restrict__ out) {
    int idx = (blockIdx.x * 256 + threadIdx.x) * 4;
    f32x4 s = {0.f, 0.f, 0.f, 0.f};
#pragma unroll
    for (int hh = 0; hh < NH3; ++hh)
        s += *(const f32x4*)&g_part[(size_t)hh * SEQ * NDIM + idx];
    *(f32x4*)&out[idx] = s;
}

extern "C" void kernel_launch(void* const* d_in, const int* in_sizes, int n_in,
                              void* d_out, int out_size, void* d_ws, size_t ws_size,
                              hipStream_t stream) {
    detect_k <<<dim3(1),        dim3(256), 0, stream>>>((const unsigned short*)d_in[8]);
    convert_k<<<dim3(768, 10),  dim3(256), 0, stream>>>(d_in[0], d_in[1], d_in[2], d_in[3],
                                                        d_in[4], d_in[5], d_in[6], d_in[7],
                                                        d_in[8], d_in[9]);
    proj_all  <<<dim3(15360),   dim3(256), 0, stream>>>();
    attn_k    <<<dim3(768),     dim3(512), 0, stream>>>();
    finalize_k<<<dim3(512),     dim3(256), 0, stream>>>((float*)d_out);
}

// Round 8
// 427.527 us; speedup vs baseline: 1.1333x; 1.1333x over previous
//
#include <hip/hip_runtime.h>
#include <hip/hip_bf16.h>

typedef __bf16 bf16;
typedef __attribute__((ext_vector_type(8)))  __bf16 bf16x8;
typedef __attribute__((ext_vector_type(4)))  __bf16 bf16x4;
typedef __attribute__((ext_vector_type(4)))  float  f32x4;

#define SEQ   2048
#define NDIM  256
#define NH3   48
#define CH    64
#define SQS   72     // sQ row stride (pad: rows advance 4 banks)
#define SPS   72     // sP row stride
#define VTS   2176   // g_vt row stride (4352B = 34 x 128B lines)

// canonical bf16 input arena offsets (elements; multiples of 8 -> 16B aligned)
#define OFF_NODES 0
#define OFF_POS   524288
#define OFF_ROT   536576
#define OFF_WN    544768
#define OFF_BN    1069056
#define OFF_WP    1071104
#define OFF_BP    1083392
#define OFF_WR    1085440
#define OFF_WV    1093632
#define OFF_BV    4239360
#define TOT_IN    4251648

__device__ bf16  g_in[TOT_IN];              // 8.5 MB canonical bf16 inputs
__device__ bf16  g_k [NH3 * SEQ * CH];      // [h][s][c] 12.6 MB
__device__ bf16  g_q [NH3 * SEQ * CH];      // [h][s][c] 12.6 MB
__device__ bf16  g_vt[NH3 * NDIM * VTS];    // [h][d][j'] padded, j-permuted per 64-block
__device__ float g_part[(size_t)NH3 * SEQ * NDIM];  // 100 MB per-head partials (no atomics)
__device__ int   g_isf32;

// ---------------------------------------------------------------- dtype probe
__global__ __launch_bounds__(256) void detect_k(const unsigned short* __restrict__ p) {
    __shared__ int cff, czero;
    if (threadIdx.x == 0) { cff = 0; czero = 0; }
    __syncthreads();
    int ff = 0, zz = 0;
    for (int r = 0; r < 64; ++r) {
        int idx = threadIdx.x * 64 + r;
        unsigned short u = p[idx];
        if (((u >> 7) & 0xFF) == 0xFF) ff++;
        if (((idx & 1) == 0) && (u == 0)) zz++;
    }
    if (ff) atomicAdd(&cff, ff);
    if (zz) atomicAdd(&czero, zz);
    __syncthreads();
    if (threadIdx.x == 0) g_isf32 = (cff > 2 || czero > 6000) ? 1 : 0;
}

// --------------------------------------------------------- input canonicalize
__global__ __launch_bounds__(256) void convert_k(
    const void* s0, const void* s1, const void* s2, const void* s3, const void* s4,
    const void* s5, const void* s6, const void* s7, const void* s8, const void* s9)
{
    const void* srcs[10] = {s0, s1, s2, s3, s4, s5, s6, s7, s8, s9};
    const int   szs[10]  = {524288, 12288, 8192, 524288, 2048, 12288, 2048, 8192, 3145728, 12288};
    const int   offs[10] = {OFF_NODES, OFF_POS, OFF_ROT, OFF_WN, OFF_BN,
                            OFF_WP, OFF_BP, OFF_WR, OFF_WV, OFF_BV};
    const int y = blockIdx.y;
    const void* src = srcs[y];
    bf16* dst = g_in + offs[y];
    const int n = szs[y];
    const int isf = g_isf32;
    const int stride = gridDim.x * 256 * 4;
    for (int i = (blockIdx.x * 256 + threadIdx.x) * 4; i < n; i += stride) {
        bf16x4 o;
        if (isf) {
            float4 v = *(const float4*)((const float*)src + i);
            o[0] = (bf16)v.x; o[1] = (bf16)v.y; o[2] = (bf16)v.z; o[3] = (bf16)v.w;
        } else {
            o = *(const bf16x4*)((const bf16*)src + i);
        }
        *(bf16x4*)(dst + i) = o;
    }
}

// ------------------------------------------------- fused projections (1 launch)
// blocks [0,1024)      : nodes -> k,q heads 0-15   (XCD-swizzled)
// blocks [1024,9216)   : pos/rot -> k,q heads 16-47
// blocks [9216,15360)  : nodes -> V (transposed+permuted), XCD-swizzled
__global__ __launch_bounds__(256) void proj_all()
{
    __shared__ __align__(16) bf16 sB[64 * 264];
    __shared__ __align__(16) bf16 sO[64 * 72];
    const int t  = threadIdx.x;
    const int gb = blockIdx.x;

    if (gb < 1024) {
        // ---------------- nodes -> k,q (heads 0-15)
        const bf16* nodes = g_in + OFF_NODES;
        const bf16* Wn    = g_in + OFF_WN;
        const bf16* bn    = g_in + OFF_BN;
        const int bx   = gb;
        const int xcd  = bx & 7;
        const int rest = bx >> 3;             // 0..127
        const int f0   = (xcd * 4 + (rest & 3)) * 64;   // 4 f-blocks per XCD
        const int s0   = (rest >> 2) * 64;              // 0..31

        for (int rep = 0; rep < 8; ++rep) {
            int idx = t + rep * 256;
            int row = idx >> 5, chunk = idx & 31;
            *(bf16x8*)&sB[row * 264 + chunk * 8] =
                *(const bf16x8*)&Wn[(f0 + row) * 256 + chunk * 8];
        }
        __syncthreads();

        const int w = t >> 6, lane = t & 63;
        const int l15 = lane & 15, quad = lane >> 4;

        f32x4 acc[4] = {{}, {}, {}, {}};
        const bf16* arow = nodes + (s0 + w * 16 + l15) * 256 + quad * 8;
#pragma unroll
        for (int kc = 0; kc < 8; ++kc) {
            bf16x8 af = *(const bf16x8*)(arow + kc * 32);
#pragma unroll
            for (int ft = 0; ft < 4; ++ft) {
                bf16x8 bfr = *(const bf16x8*)&sB[(ft * 16 + l15) * 264 + kc * 32 + quad * 8];
                acc[ft] = __builtin_amdgcn_mfma_f32_16x16x32_bf16(af, bfr, acc[ft], 0, 0, 0);
            }
        }
#pragma unroll
        for (int ft = 0; ft < 4; ++ft) {
            int f = f0 + ft * 16 + l15;
            float bias = (float)bn[f];
            int h = f >> 7, c2 = f & 127;
            bf16* base = (c2 < 64) ? (g_k + h * SEQ * CH + c2)
                                   : (g_q + h * SEQ * CH + (c2 - 64));
#pragma unroll
            for (int r = 0; r < 4; ++r) {
                int s = s0 + w * 16 + quad * 4 + r;
                base[s * CH] = (bf16)(acc[ft][r] + bias);
            }
        }
    } else if (gb < 9216) {
        // ---------------- pos/rot -> k,q (heads 16-31 / 32-47)
        const bf16* pos  = g_in + OFF_POS;
        const bf16* rotq = g_in + OFF_ROT;
        const bf16* Wp   = g_in + OFF_WP;
        const bf16* bp   = g_in + OFF_BP;
        const bf16* Wr   = g_in + OFF_WR;
        int id = (gb - 1024) * 256 + t;           // 2 * 2048 * 512
        int fg  = id & 511;                        // f-group of 4
        int s   = (id >> 9) & 2047;
        int src = id >> 20;
        int f0  = fg * 4;
        float y[4]; int h;
        if (src == 0) {
#pragma unroll
            for (int j = 0; j < 4; ++j) {
                float a = (float)bp[f0 + j];
#pragma unroll
                for (int x = 0; x < 6; ++x)
                    a += (float)pos[s * 6 + x] * (float)Wp[(f0 + j) * 6 + x];
                y[j] = a;
            }
            h = 16 + (f0 >> 7);
        } else {
#pragma unroll
            for (int j = 0; j < 4; ++j) {
                float a = 0.f;
#pragma unroll
                for (int x = 0; x < 4; ++x)
                    a += (float)rotq[s * 4 + x] * (float)Wr[(f0 + j) * 4 + x];
                y[j] = a;
            }
            h = 32 + (f0 >> 7);
        }
        bf16x4 o;
#pragma unroll
        for (int j = 0; j < 4; ++j) o[j] = (bf16)y[j];
        int c2 = f0 & 127;
        if (c2 < 64) *(bf16x4*)&g_k[(h * SEQ + s) * CH + c2]        = o;
        else         *(bf16x4*)&g_q[(h * SEQ + s) * CH + (c2 - 64)] = o;
    } else {
        // ---------------- nodes -> V (transposed + j-permuted, padded stride)
        const bf16* nodes = g_in + OFF_NODES;
        const bf16* Wv    = g_in + OFF_WV;
        const bf16* bv    = g_in + OFF_BV;
        const int bx   = gb - 9216;           // 0..6143
        const int xcd  = bx & 7;
        const int rest = bx >> 3;             // 0..767
        const int f0   = (xcd * 24 + (rest % 24)) * 64;  // 24 f-blocks per XCD
        const int s0   = (rest / 24) * 64;               // 0..31

        for (int rep = 0; rep < 8; ++rep) {
            int idx = t + rep * 256;
            int row = idx >> 5, chunk = idx & 31;
            *(bf16x8*)&sB[row * 264 + chunk * 8] =
                *(const bf16x8*)&Wv[(size_t)(f0 + row) * 256 + chunk * 8];
        }
        __syncthreads();

        const int w = t >> 6, lane = t & 63;
        const int l15 = lane & 15, quad = lane >> 4;

        f32x4 acc[4] = {{}, {}, {}, {}};
        const bf16* arow = nodes + (s0 + w * 16 + l15) * 256 + quad * 8;
#pragma unroll
        for (int kc = 0; kc < 8; ++kc) {
            bf16x8 af = *(const bf16x8*)(arow + kc * 32);
#pragma unroll
            for (int ft = 0; ft < 4; ++ft) {
                bf16x8 bfr = *(const bf16x8*)&sB[(ft * 16 + l15) * 264 + kc * 32 + quad * 8];
                acc[ft] = __builtin_amdgcn_mfma_f32_16x16x32_bf16(af, bfr, acc[ft], 0, 0, 0);
            }
        }
        __syncthreads();
#pragma unroll
        for (int ft = 0; ft < 4; ++ft) {
            int n = f0 + ft * 16 + l15;
            float bias = (float)bv[n];
#pragma unroll
            for (int r = 0; r < 4; ++r) {
                // s-local l = w*16+quad*4+r -> j' = (quad*4+r)*4 + w
                sO[(ft * 16 + l15) * 72 + (quad * 4 + r) * 4 + w] = (bf16)(acc[ft][r] + bias);
            }
        }
        __syncthreads();
        for (int rep = 0; rep < 2; ++rep) {
            int idx = t + rep * 256;
            int row = idx >> 3, chunk = idx & 7;
            *(bf16x8*)&g_vt[(size_t)(f0 + row) * VTS + s0 + chunk * 8] =
                *(const bf16x8*)&sO[row * 72 + chunk * 8];
        }
    }
}

// ------------------------------------------------------------- attention
// R19 = R11 structure with ONE change: sV eliminated (the clean test R12
// never ran — R12 confounded sV-removal with a barrier restructure).
// Rationale (R18 post-mortem analysis): R11 is ~80% LDS-issue bound
// (41 LDS instrs/lane/step ~= 370cy/wave-step x 16 waves ~= 5900 of 7280
// cyc/step/CU). sV is 12 of those 41 instrs (write 4 + read 8) for data
// read only 2x after staging — the worst staging economics in the kernel.
// V fragments now read direct from g_vt (L2/L3-resident; 6MB/XCD):
//   vf0 (kc=0) issued pre-B2 (cover = barrier + ap0 ds_reads ~ 200cy);
//   vf1 (kc=1) issued under ap0 reads + kc0 MFMA cluster.
// B2/B3 weakened to lgkm-only barriers (R18-proven correct) so vf waits are
// per-wave counted vmcnt, not all-wave drains. Register ledger: vpre dies
// (-16), vf0 (+16) net zero at B2; peak PV ~60 <= 64 (no spill; sentinel =
// WRITE_SIZE must stay ~109MB, VGPR_Count 64).
// Failed grafts (keep away): s_setprio (R13), sP 64+XOR (R14), work
// stealing (R16), issue-early qpre/vpre (R18: scratch spill +371MB writes).
__global__ __launch_bounds__(512, 4) void attn_k()
{
    const int bx  = blockIdx.x;
    const int xcd = bx & 7;
    const int sub = bx >> 3;             // 0..95
    const int h   = xcd * 6 + (sub % 6); // 6 heads per XCD
    const int it  = sub / 6;             // 0..15
    const int i0  = it * 128;
    const int t   = threadIdx.x;
    const int w   = t >> 6, lane = t & 63;
    const int l15 = lane & 15, quad = lane >> 4;
    const bool rot = (h >= 32);

    __shared__ __align__(16) bf16 sQ[64 * SQS];      //  9216 B
    __shared__ __align__(16) bf16 sP[128 * SPS];     // 18432 B
    __shared__ float sL[128];                        //   512 B (total 28160)

    const bf16* kb = g_k  + h * SEQ * CH;
    const bf16* qb = g_q  + h * SEQ * CH;
    const bf16* vb = g_vt + (size_t)h * NDIM * VTS;

    // K fragments: wave w owns S-rows i0 + w*16 .. +16
    bf16x8 kf0 = *(const bf16x8*)&kb[(i0 + w * 16 + l15) * CH + quad * 8];
    bf16x8 kf1 = *(const bf16x8*)&kb[(i0 + w * 16 + l15) * CH + 32 + quad * 8];

    // PV split: i-half ih = w>>2 (64 rows), d-quarter dq = w&3 (64 cols)
    const int ih = w >> 2, dq = w & 3;

    // staging decomposition (16B chunks)
    const int qrow = t >> 3, qch = t & 7;

    // per-lane V base: row = dq*64 + l15 (+ dt*16 below), col base quad*8
    const bf16* vbase = vb + (size_t)(dq * 64 + l15) * VTS + quad * 8;

    f32x4 acc[4][4];
#pragma unroll
    for (int a = 0; a < 4; ++a)
#pragma unroll
        for (int b = 0; b < 4; ++b) acc[a][b] = (f32x4){0.f, 0.f, 0.f, 0.f};
    f32x4 lp = {0.f, 0.f, 0.f, 0.f};

    // prologue: stage Q tile for step 0 (sV staging gone)
    bf16x8 qpre = *(const bf16x8*)&qb[t * 8];
    *(bf16x8*)&sQ[qrow * SQS + qch * 8] = qpre;
    __syncthreads();                                   // B1 (step 0)

    for (int st = 0; st < 32; ++st) {
        // ---- S phase: 16 i-rows x 64 j per wave
        f32x4 sjb[4];
#pragma unroll
        for (int jb = 0; jb < 4; ++jb) {
            bf16x8 q0 = *(const bf16x8*)&sQ[(jb * 16 + l15) * SQS + quad * 8];
            bf16x8 q1 = *(const bf16x8*)&sQ[(jb * 16 + l15) * SQS + 32 + quad * 8];
            f32x4 sa = {};
            sa = __builtin_amdgcn_mfma_f32_16x16x32_bf16(kf0, q0, sa, 0, 0, 0);
            sa = __builtin_amdgcn_mfma_f32_16x16x32_bf16(kf1, q1, sa, 0, 0, 0);
            sjb[jb] = sa;
        }

        // ---- P phase: exp + pack; column j' = l15*4 + jb (logical j = jb*16+l15)
#pragma unroll
        for (int r = 0; r < 4; ++r) {
            bf16x4 pk;
#pragma unroll
            for (int jb = 0; jb < 4; ++jb) {
                float d = sjb[jb][r];
                float x = rot ? (d * d * 0.25f) : (d * 0.25f);
                x = fminf(x, 60.f);
                float p = __expf(x);
                lp[r] += p;
                pk[jb] = (bf16)p;
            }
            *(bf16x4*)&sP[(w * 16 + quad * 4 + r) * SPS + l15 * 4] = pk;
        }

        // ---- issue kc=0 V fragments (global, L2/L3); cover = B2 wait + ap0 reads
        const bf16* vs = vbase + st * 64;
        bf16x8 vf0[4];
#pragma unroll
        for (int dt = 0; dt < 4; ++dt)
            vf0[dt] = *(const bf16x8*)&vs[(size_t)dt * (16 * VTS)];

        // ---- B2 (weak): sP visible; vf0 stays in flight (per-wave counted wait)
        asm volatile("s_waitcnt lgkmcnt(0)" ::: "memory");
        __builtin_amdgcn_s_barrier();
        __builtin_amdgcn_sched_barrier(0);

        // ---- PV phase: wave w owns (ih, dq): 64 i x 64 d
        bf16x8 ap0[4];
#pragma unroll
        for (int itr = 0; itr < 4; ++itr)
            ap0[itr] = *(const bf16x8*)&sP[(ih * 64 + itr * 16 + l15) * SPS + quad * 8];
        // kc=1 V fragments + next-step Q issued here (covered by kc0 MFMAs)
        bf16x8 vf1[4];
#pragma unroll
        for (int dt = 0; dt < 4; ++dt)
            vf1[dt] = *(const bf16x8*)&vs[(size_t)dt * (16 * VTS) + 32];
        if (st < 31) qpre = *(const bf16x8*)&qb[(st + 1) * 4096 + t * 8];

#pragma unroll
        for (int itr = 0; itr < 4; ++itr)
#pragma unroll
            for (int dt = 0; dt < 4; ++dt)
                acc[itr][dt] = __builtin_amdgcn_mfma_f32_16x16x32_bf16(
                    ap0[itr], vf0[dt], acc[itr][dt], 0, 0, 0);

        bf16x8 ap1[4];
#pragma unroll
        for (int itr = 0; itr < 4; ++itr)
            ap1[itr] = *(const bf16x8*)&sP[(ih * 64 + itr * 16 + l15) * SPS + 32 + quad * 8];
#pragma unroll
        for (int itr = 0; itr < 4; ++itr)
#pragma unroll
            for (int dt = 0; dt < 4; ++dt)
                acc[itr][dt] = __builtin_amdgcn_mfma_f32_16x16x32_bf16(
                    ap1[itr], vf1[dt], acc[itr][dt], 0, 0, 0);

        // ---- B3 (weak): all sP/sQ reads done; qpre may still be in flight
        asm volatile("s_waitcnt lgkmcnt(0)" ::: "memory");
        __builtin_amdgcn_s_barrier();
        __builtin_amdgcn_sched_barrier(0);

        // ---- stage next step's Q (compiler inserts counted vmcnt for qpre)
        if (st < 31) {
            *(bf16x8*)&sQ[qrow * SQS + qch * 8] = qpre;
            __syncthreads();                           // B1 (full): staging visible
        }
    }

    // l reduce across the 16 j-lanes (wave w owns S-rows w*16..+16)
#pragma unroll
    for (int off = 1; off < 16; off <<= 1) {
#pragma unroll
        for (int r = 0; r < 4; ++r) lp[r] += __shfl_xor(lp[r], off, 64);
    }
    if (l15 == 0) *(f32x4*)&sL[w * 16 + quad * 4] = lp;
    __syncthreads();

    // normalize + plain stores into this head's private partial plane
    float* pb = g_part + (size_t)h * SEQ * NDIM;
#pragma unroll
    for (int itr = 0; itr < 4; ++itr) {
        f32x4 lv = *(const f32x4*)&sL[ih * 64 + itr * 16 + quad * 4];
#pragma unroll
        for (int r = 0; r < 4; ++r) {
            float inv = 1.0f / lv[r];
            float* ob = &pb[(size_t)(i0 + ih * 64 + itr * 16 + quad * 4 + r) * NDIM + dq * 64 + l15];
#pragma unroll
            for (int dt = 0; dt < 4; ++dt)
                ob[dt * 16] = acc[itr][dt][r] * inv;
        }
    }
}

// ------------------------------------------- finalize: sum 48 head planes
__global__ __launch_bounds__(256) void finalize_k(float* __restrict__ out) {
    int idx = (blockIdx.x * 256 + threadIdx.x) * 4;
    f32x4 s = {0.f, 0.f, 0.f, 0.f};
#pragma unroll
    for (int hh = 0; hh < NH3; ++hh)
        s += *(const f32x4*)&g_part[(size_t)hh * SEQ * NDIM + idx];
    *(f32x4*)&out[idx] = s;
}

extern "C" void kernel_launch(void* const* d_in, const int* in_sizes, int n_in,
                              void* d_out, int out_size, void* d_ws, size_t ws_size,
                              hipStream_t stream) {
    detect_k <<<dim3(1),        dim3(256), 0, stream>>>((const unsigned short*)d_in[8]);
    convert_k<<<dim3(768, 10),  dim3(256), 0, stream>>>(d_in[0], d_in[1], d_in[2], d_in[3],
                                                        d_in[4], d_in[5], d_in[6], d_in[7],
                                                        d_in[8], d_in[9]);
    proj_all  <<<dim3(15360),   dim3(256), 0, stream>>>();
    attn_k    <<<dim3(768),     dim3(512), 0, stream>>>();
    finalize_k<<<dim3(512),     dim3(256), 0, stream>>>((float*)d_out);
}

// Round 9
// 356.555 us; speedup vs baseline: 1.3588x; 1.1990x over previous
//
#include <hip/hip_runtime.h>
#include <hip/hip_bf16.h>

typedef __bf16 bf16;
typedef __attribute__((ext_vector_type(8)))  __bf16 bf16x8;
typedef __attribute__((ext_vector_type(4)))  __bf16 bf16x4;
typedef __attribute__((ext_vector_type(4)))  float  f32x4;

#define SEQ   2048
#define NDIM  256
#define NH3   48
#define CH    64
#define SQS   72     // sQ row stride (pad: rows advance 4 banks)
#define SVS   72     // sV row stride
#define SPS   72     // sP row stride
#define VTS   2176   // g_vt row stride (4352B = 17 x 256B sectors)

// canonical bf16 input arena offsets (elements; multiples of 8 -> 16B aligned)
#define OFF_NODES 0
#define OFF_POS   524288
#define OFF_ROT   536576
#define OFF_WN    544768
#define OFF_BN    1069056
#define OFF_WP    1071104
#define OFF_BP    1083392
#define OFF_WR    1085440
#define OFF_WV    1093632
#define OFF_BV    4239360
#define TOT_IN    4251648

__device__ bf16  g_in[TOT_IN];              // 8.5 MB canonical bf16 inputs
__device__ bf16  g_k [NH3 * SEQ * CH];      // [h][s][c] 12.6 MB
__device__ bf16  g_q [NH3 * SEQ * CH];      // [h][s][c] 12.6 MB
__device__ bf16  g_vt[NH3 * NDIM * VTS];    // [h][d][j'] padded, j-permuted per 64-block
__device__ float g_part[(size_t)2 * NH3 * SEQ * NDIM]; // 201 MB: [jh*48+h][i][d] UNNORMALIZED
__device__ float g_l   [2 * NH3 * SEQ];     // per-(jh,h,i) softmax partial sums
__device__ float g_invl[NH3 * SEQ];         // 1/(l0+l1)
__device__ int   g_isf32;

// ---------------------------------------------------------------- dtype probe
__global__ __launch_bounds__(256) void detect_k(const unsigned short* __restrict__ p) {
    __shared__ int cff, czero;
    if (threadIdx.x == 0) { cff = 0; czero = 0; }
    __syncthreads();
    int ff = 0, zz = 0;
    for (int r = 0; r < 64; ++r) {
        int idx = threadIdx.x * 64 + r;
        unsigned short u = p[idx];
        if (((u >> 7) & 0xFF) == 0xFF) ff++;
        if (((idx & 1) == 0) && (u == 0)) zz++;
    }
    if (ff) atomicAdd(&cff, ff);
    if (zz) atomicAdd(&czero, zz);
    __syncthreads();
    if (threadIdx.x == 0) g_isf32 = (cff > 2 || czero > 6000) ? 1 : 0;
}

// --------------------------------------------------------- input canonicalize
__global__ __launch_bounds__(256) void convert_k(
    const void* s0, const void* s1, const void* s2, const void* s3, const void* s4,
    const void* s5, const void* s6, const void* s7, const void* s8, const void* s9)
{
    const void* srcs[10] = {s0, s1, s2, s3, s4, s5, s6, s7, s8, s9};
    const int   szs[10]  = {524288, 12288, 8192, 524288, 2048, 12288, 2048, 8192, 3145728, 12288};
    const int   offs[10] = {OFF_NODES, OFF_POS, OFF_ROT, OFF_WN, OFF_BN,
                            OFF_WP, OFF_BP, OFF_WR, OFF_WV, OFF_BV};
    const int y = blockIdx.y;
    const void* src = srcs[y];
    bf16* dst = g_in + offs[y];
    const int n = szs[y];
    const int isf = g_isf32;
    const int stride = gridDim.x * 256 * 4;
    for (int i = (blockIdx.x * 256 + threadIdx.x) * 4; i < n; i += stride) {
        bf16x4 o;
        if (isf) {
            float4 v = *(const float4*)((const float*)src + i);
            o[0] = (bf16)v.x; o[1] = (bf16)v.y; o[2] = (bf16)v.z; o[3] = (bf16)v.w;
        } else {
            o = *(const bf16x4*)((const bf16*)src + i);
        }
        *(bf16x4*)(dst + i) = o;
    }
}

// ------------------------------------------------- fused projections (1 launch)
// blocks [0,1024)      : nodes -> k,q heads 0-15   (XCD-swizzled)
// blocks [1024,9216)   : pos/rot -> k,q heads 16-47
// blocks [9216,15360)  : nodes -> V (transposed+permuted), XCD-swizzled
__global__ __launch_bounds__(256) void proj_all()
{
    __shared__ __align__(16) bf16 sB[64 * 264];
    __shared__ __align__(16) bf16 sO[64 * 72];
    const int t  = threadIdx.x;
    const int gb = blockIdx.x;

    if (gb < 1024) {
        // ---------------- nodes -> k,q (heads 0-15)
        const bf16* nodes = g_in + OFF_NODES;
        const bf16* Wn    = g_in + OFF_WN;
        const bf16* bn    = g_in + OFF_BN;
        const int bx   = gb;
        const int xcd  = bx & 7;
        const int rest = bx >> 3;             // 0..127
        const int f0   = (xcd * 4 + (rest & 3)) * 64;   // 4 f-blocks per XCD
        const int s0   = (rest >> 2) * 64;              // 0..31

        for (int rep = 0; rep < 8; ++rep) {
            int idx = t + rep * 256;
            int row = idx >> 5, chunk = idx & 31;
            *(bf16x8*)&sB[row * 264 + chunk * 8] =
                *(const bf16x8*)&Wn[(f0 + row) * 256 + chunk * 8];
        }
        __syncthreads();

        const int w = t >> 6, lane = t & 63;
        const int l15 = lane & 15, quad = lane >> 4;

        f32x4 acc[4] = {{}, {}, {}, {}};
        const bf16* arow = nodes + (s0 + w * 16 + l15) * 256 + quad * 8;
#pragma unroll
        for (int kc = 0; kc < 8; ++kc) {
            bf16x8 af = *(const bf16x8*)(arow + kc * 32);
#pragma unroll
            for (int ft = 0; ft < 4; ++ft) {
                bf16x8 bfr = *(const bf16x8*)&sB[(ft * 16 + l15) * 264 + kc * 32 + quad * 8];
                acc[ft] = __builtin_amdgcn_mfma_f32_16x16x32_bf16(af, bfr, acc[ft], 0, 0, 0);
            }
        }
#pragma unroll
        for (int ft = 0; ft < 4; ++ft) {
            int f = f0 + ft * 16 + l15;
            float bias = (float)bn[f];
            int h = f >> 7, c2 = f & 127;
            bf16* base = (c2 < 64) ? (g_k + h * SEQ * CH + c2)
                                   : (g_q + h * SEQ * CH + (c2 - 64));
#pragma unroll
            for (int r = 0; r < 4; ++r) {
                int s = s0 + w * 16 + quad * 4 + r;
                base[s * CH] = (bf16)(acc[ft][r] + bias);
            }
        }
    } else if (gb < 9216) {
        // ---------------- pos/rot -> k,q (heads 16-31 / 32-47)
        const bf16* pos  = g_in + OFF_POS;
        const bf16* rotq = g_in + OFF_ROT;
        const bf16* Wp   = g_in + OFF_WP;
        const bf16* bp   = g_in + OFF_BP;
        const bf16* Wr   = g_in + OFF_WR;
        int id = (gb - 1024) * 256 + t;           // 2 * 2048 * 512
        int fg  = id & 511;                        // f-group of 4
        int s   = (id >> 9) & 2047;
        int src = id >> 20;
        int f0  = fg * 4;
        float y[4]; int h;
        if (src == 0) {
#pragma unroll
            for (int j = 0; j < 4; ++j) {
                float a = (float)bp[f0 + j];
#pragma unroll
                for (int x = 0; x < 6; ++x)
                    a += (float)pos[s * 6 + x] * (float)Wp[(f0 + j) * 6 + x];
                y[j] = a;
            }
            h = 16 + (f0 >> 7);
        } else {
#pragma unroll
            for (int j = 0; j < 4; ++j) {
                float a = 0.f;
#pragma unroll
                for (int x = 0; x < 4; ++x)
                    a += (float)rotq[s * 4 + x] * (float)Wr[(f0 + j) * 4 + x];
                y[j] = a;
            }
            h = 32 + (f0 >> 7);
        }
        bf16x4 o;
#pragma unroll
        for (int j = 0; j < 4; ++j) o[j] = (bf16)y[j];
        int c2 = f0 & 127;
        if (c2 < 64) *(bf16x4*)&g_k[(h * SEQ + s) * CH + c2]        = o;
        else         *(bf16x4*)&g_q[(h * SEQ + s) * CH + (c2 - 64)] = o;
    } else {
        // ---------------- nodes -> V (transposed + j-permuted, padded stride)
        const bf16* nodes = g_in + OFF_NODES;
        const bf16* Wv    = g_in + OFF_WV;
        const bf16* bv    = g_in + OFF_BV;
        const int bx   = gb - 9216;           // 0..6143
        const int xcd  = bx & 7;
        const int rest = bx >> 3;             // 0..767
        const int f0   = (xcd * 24 + (rest % 24)) * 64;  // 24 f-blocks per XCD
        const int s0   = (rest / 24) * 64;               // 0..31

        for (int rep = 0; rep < 8; ++rep) {
            int idx = t + rep * 256;
            int row = idx >> 5, chunk = idx & 31;
            *(bf16x8*)&sB[row * 264 + chunk * 8] =
                *(const bf16x8*)&Wv[(size_t)(f0 + row) * 256 + chunk * 8];
        }
        __syncthreads();

        const int w = t >> 6, lane = t & 63;
        const int l15 = lane & 15, quad = lane >> 4;

        f32x4 acc[4] = {{}, {}, {}, {}};
        const bf16* arow = nodes + (s0 + w * 16 + l15) * 256 + quad * 8;
#pragma unroll
        for (int kc = 0; kc < 8; ++kc) {
            bf16x8 af = *(const bf16x8*)(arow + kc * 32);
#pragma unroll
            for (int ft = 0; ft < 4; ++ft) {
                bf16x8 bfr = *(const bf16x8*)&sB[(ft * 16 + l15) * 264 + kc * 32 + quad * 8];
                acc[ft] = __builtin_amdgcn_mfma_f32_16x16x32_bf16(af, bfr, acc[ft], 0, 0, 0);
            }
        }
        __syncthreads();
#pragma unroll
        for (int ft = 0; ft < 4; ++ft) {
            int n = f0 + ft * 16 + l15;
            float bias = (float)bv[n];
#pragma unroll
            for (int r = 0; r < 4; ++r) {
                // s-local l = w*16+quad*4+r -> j' = (quad*4+r)*4 + w
                sO[(ft * 16 + l15) * 72 + (quad * 4 + r) * 4 + w] = (bf16)(acc[ft][r] + bias);
            }
        }
        __syncthreads();
        for (int rep = 0; rep < 2; ++rep) {
            int idx = t + rep * 256;
            int row = idx >> 3, chunk = idx & 7;
            *(bf16x8*)&g_vt[(size_t)(f0 + row) * VTS + s0 + chunk * 8] =
                *(const bf16x8*)&sO[row * 72 + chunk * 8];
        }
    }
}

// ------------------------------------------------------------- attention
// R20 = R11 inner loop VERBATIM, but each block handles HALF the j-range
// (16 steps instead of 32) -> grid 1536 = exactly 3 full rounds of the 512
// resident slots (2 blocks/CU x 256 CU). Rationale: occupancy 35.7% vs the
// 50% cap solves to a 2-then-1 block schedule where the lone tail block runs
// ~1.35x slower per step (2 waves/SIMD can't self-hide latency); makespan
// ~75 step-times. With 3 exact dual-resident rounds: 48 step-times.
// Blocks store UNNORMALIZED partials to their private (jh,h) plane + the
// per-row softmax partial sums l; invl_k combines l-halves; finalize_k sums
// 96 planes x invl. (Numerically identical up to f32 reassociation.)
// Failed grafts (keep away): sV-from-global (R12/R19: latency-bound at 16
// waves/CU — LDS staging IS the latency-hiding), s_setprio (R13: FETCH 4x),
// sP 64+XOR (R14: +38us), work stealing (R16), issue-early qpre/vpre (R18:
// scratch spill). R11's intra-block structure is a verified local optimum.
__global__ __launch_bounds__(512, 4) void attn_k()
{
    const int bx  = blockIdx.x;
    const int xcd = bx & 7;
    const int sub = bx >> 3;             // 0..191
    const int h   = xcd * 6 + (sub % 6); // 6 heads per XCD
    const int rest = sub / 6;            // 0..31
    const int it  = rest & 15;           // i-tile 0..15
    const int jh  = rest >> 4;           // j-half 0..1
    const int i0  = it * 128;
    const int t   = threadIdx.x;
    const int w   = t >> 6, lane = t & 63;
    const int l15 = lane & 15, quad = lane >> 4;
    const bool rot = (h >= 32);

    __shared__ __align__(16) bf16 sQ[64 * SQS];      //  9216 B
    __shared__ __align__(16) bf16 sV[256 * SVS];     // 36864 B
    __shared__ __align__(16) bf16 sP[128 * SPS];     // 18432 B (total 64512)

    const bf16* kb = g_k  + h * SEQ * CH;
    const bf16* qb = g_q  + h * SEQ * CH + jh * 16 * 4096;          // j-half base
    const bf16* vb = g_vt + (size_t)h * NDIM * VTS;
    const int   jcol0 = jh * 16 * 64;                                // j'-half base in g_vt rows

    // K fragments: wave w owns S-rows i0 + w*16 .. +16
    bf16x8 kf0 = *(const bf16x8*)&kb[(i0 + w * 16 + l15) * CH + quad * 8];
    bf16x8 kf1 = *(const bf16x8*)&kb[(i0 + w * 16 + l15) * CH + 32 + quad * 8];

    // PV split: i-half ih = w>>2 (64 rows), d-quarter dq = w&3 (64 cols)
    const int ih = w >> 2, dq = w & 3;

    // staging decomposition (16B chunks)
    const int qrow = t >> 3, qch = t & 7;

    f32x4 acc[4][4];
#pragma unroll
    for (int a = 0; a < 4; ++a)
#pragma unroll
        for (int b = 0; b < 4; ++b) acc[a][b] = (f32x4){0.f, 0.f, 0.f, 0.f};
    f32x4 lp = {0.f, 0.f, 0.f, 0.f};

    // prefetch step 0 into regs
    bf16x8 qpre, vpre[4];
    qpre = *(const bf16x8*)&qb[t * 8];
#pragma unroll
    for (int rep = 0; rep < 4; ++rep) {
        int idx = t + rep * 512;
        vpre[rep] = *(const bf16x8*)&vb[(size_t)(idx >> 3) * VTS + jcol0 + (idx & 7) * 8];
    }
    // write step 0 to LDS
    *(bf16x8*)&sQ[qrow * SQS + qch * 8] = qpre;
#pragma unroll
    for (int rep = 0; rep < 4; ++rep) {
        int idx = t + rep * 512;
        *(bf16x8*)&sV[(idx >> 3) * SVS + (idx & 7) * 8] = vpre[rep];
    }
    __syncthreads();                                   // B1 (step 0)

    for (int st = 0; st < 16; ++st) {
        // ---- S phase: 16 i-rows x 64 j per wave
        f32x4 sjb[4];
#pragma unroll
        for (int jb = 0; jb < 4; ++jb) {
            bf16x8 q0 = *(const bf16x8*)&sQ[(jb * 16 + l15) * SQS + quad * 8];
            bf16x8 q1 = *(const bf16x8*)&sQ[(jb * 16 + l15) * SQS + 32 + quad * 8];
            f32x4 sa = {};
            sa = __builtin_amdgcn_mfma_f32_16x16x32_bf16(kf0, q0, sa, 0, 0, 0);
            sa = __builtin_amdgcn_mfma_f32_16x16x32_bf16(kf1, q1, sa, 0, 0, 0);
            sjb[jb] = sa;
        }

        // ---- P phase: exp + pack; column j' = l15*4 + jb (logical j = jb*16+l15)
#pragma unroll
        for (int r = 0; r < 4; ++r) {
            bf16x4 pk;
#pragma unroll
            for (int jb = 0; jb < 4; ++jb) {
                float d = sjb[jb][r];
                float x = rot ? (d * d * 0.25f) : (d * 0.25f);
                x = fminf(x, 60.f);
                float p = __expf(x);
                lp[r] += p;
                pk[jb] = (bf16)p;
            }
            *(bf16x4*)&sP[(w * 16 + quad * 4 + r) * SPS + l15 * 4] = pk;
        }
        __syncthreads();                               // B2: sP visible

        // ---- issue next step's global loads (drain at B3, covered by PV)
        if (st < 15) {
            const bf16* qn = qb + (st + 1) * 4096;
            const bf16* vn = vb + jcol0 + (st + 1) * 64;
            qpre = *(const bf16x8*)&qn[t * 8];
#pragma unroll
            for (int rep = 0; rep < 4; ++rep) {
                int idx = t + rep * 512;
                vpre[rep] = *(const bf16x8*)&vn[(size_t)(idx >> 3) * VTS + (idx & 7) * 8];
            }
        }

        // ---- PV phase: wave w owns (ih, dq): 64 i x 64 d
#pragma unroll
        for (int kc = 0; kc < 2; ++kc) {
            bf16x8 ap[4], vf[4];
#pragma unroll
            for (int itr = 0; itr < 4; ++itr)
                ap[itr] = *(const bf16x8*)&sP[(ih * 64 + itr * 16 + l15) * SPS + kc * 32 + quad * 8];
#pragma unroll
            for (int dt = 0; dt < 4; ++dt)
                vf[dt] = *(const bf16x8*)&sV[(dq * 64 + dt * 16 + l15) * SVS + kc * 32 + quad * 8];
#pragma unroll
            for (int itr = 0; itr < 4; ++itr)
#pragma unroll
                for (int dt = 0; dt < 4; ++dt)
                    acc[itr][dt] = __builtin_amdgcn_mfma_f32_16x16x32_bf16(
                        ap[itr], vf[dt], acc[itr][dt], 0, 0, 0);
        }
        __syncthreads();                               // B3: all LDS reads done

        // ---- write staged regs for next step
        if (st < 15) {
            *(bf16x8*)&sQ[qrow * SQS + qch * 8] = qpre;
#pragma unroll
            for (int rep = 0; rep < 4; ++rep) {
                int idx = t + rep * 512;
                *(bf16x8*)&sV[(idx >> 3) * SVS + (idx & 7) * 8] = vpre[rep];
            }
            __syncthreads();                           // B1: staging visible
        }
    }

    // l reduce across the 16 j-lanes (wave w owns S-rows w*16..+16) -> g_l
#pragma unroll
    for (int off = 1; off < 16; off <<= 1) {
#pragma unroll
        for (int r = 0; r < 4; ++r) lp[r] += __shfl_xor(lp[r], off, 64);
    }
    if (l15 == 0)
        *(f32x4*)&g_l[(jh * NH3 + h) * SEQ + i0 + w * 16 + quad * 4] = lp;

    // UNNORMALIZED partial stores into this block's private (jh,h) plane
    float* pb = g_part + (size_t)(jh * NH3 + h) * SEQ * NDIM;
#pragma unroll
    for (int itr = 0; itr < 4; ++itr) {
#pragma unroll
        for (int r = 0; r < 4; ++r) {
            float* ob = &pb[(size_t)(i0 + ih * 64 + itr * 16 + quad * 4 + r) * NDIM + dq * 64 + l15];
#pragma unroll
            for (int dt = 0; dt < 4; ++dt)
                ob[dt * 16] = acc[itr][dt][r];
        }
    }
}

// ----------------------------------------- invl: 1/(l_half0 + l_half1)
__global__ __launch_bounds__(256) void invl_k() {
    int idx = (blockIdx.x * 256 + threadIdx.x) * 4;   // 96 blocks -> 98304 values
    f32x4 a = *(const f32x4*)&g_l[idx];
    f32x4 b = *(const f32x4*)&g_l[NH3 * SEQ + idx];
    f32x4 o;
#pragma unroll
    for (int j = 0; j < 4; ++j) o[j] = 1.0f / (a[j] + b[j]);
    *(f32x4*)&g_invl[idx] = o;
}

// ------------------- finalize: sum 96 unnormalized planes x invl weights
__global__ __launch_bounds__(256) void finalize_k(float* __restrict__ out) {
    int idx = (blockIdx.x * 256 + threadIdx.x) * 4;
    int i = idx >> 8;                                  // NDIM = 256
    f32x4 s = {0.f, 0.f, 0.f, 0.f};
#pragma unroll
    for (int hh = 0; hh < NH3; ++hh) {
        f32x4 a = *(const f32x4*)&g_part[(size_t)hh * SEQ * NDIM + idx];
        f32x4 b = *(const f32x4*)&g_part[(size_t)(NH3 + hh) * SEQ * NDIM + idx];
        float wv = g_invl[hh * SEQ + i];
#pragma unroll
        for (int j = 0; j < 4; ++j) s[j] += (a[j] + b[j]) * wv;
    }
    *(f32x4*)&out[idx] = s;
}

extern "C" void kernel_launch(void* const* d_in, const int* in_sizes, int n_in,
                              void* d_out, int out_size, void* d_ws, size_t ws_size,
                              hipStream_t stream) {
    detect_k <<<dim3(1),        dim3(256), 0, stream>>>((const unsigned short*)d_in[8]);
    convert_k<<<dim3(768, 10),  dim3(256), 0, stream>>>(d_in[0], d_in[1], d_in[2], d_in[3],
                                                        d_in[4], d_in[5], d_in[6], d_in[7],
                                                        d_in[8], d_in[9]);
    proj_all  <<<dim3(15360),   dim3(256), 0, stream>>>();
    attn_k    <<<dim3(1536),    dim3(512), 0, stream>>>();
    invl_k    <<<dim3(96),      dim3(256), 0, stream>>>();
    finalize_k<<<dim3(512),     dim3(256), 0, stream>>>((float*)d_out);
}

// Round 10
// 332.305 us; speedup vs baseline: 1.4580x; 1.0730x over previous
//
#include <hip/hip_runtime.h>
#include <hip/hip_bf16.h>

typedef __bf16 bf16;
typedef __attribute__((ext_vector_type(8)))  __bf16 bf16x8;
typedef __attribute__((ext_vector_type(4)))  __bf16 bf16x4;
typedef __attribute__((ext_vector_type(4)))  float  f32x4;

#define SEQ   2048
#define NDIM  256
#define NH3   48
#define CH    64
#define SQS   72     // sQ row stride (pad: rows advance 4 banks)
#define SVS   72     // sV row stride
#define SPS   72     // sP row stride
#define VTS   2176   // g_vt row stride (4352B = 17 x 256B sectors)

// canonical bf16 input arena offsets (elements; multiples of 8 -> 16B aligned)
#define OFF_NODES 0
#define OFF_POS   524288
#define OFF_ROT   536576
#define OFF_WN    544768
#define OFF_BN    1069056
#define OFF_WP    1071104
#define OFF_BP    1083392
#define OFF_WR    1085440
#define OFF_WV    1093632
#define OFF_BV    4239360
#define TOT_IN    4251648

__device__ bf16  g_in[TOT_IN];              // 8.5 MB canonical bf16 inputs
__device__ bf16  g_k [NH3 * SEQ * CH];      // [h][s][c] 12.6 MB (PRE-SCALED)
__device__ bf16  g_q [NH3 * SEQ * CH];      // [h][s][c] 12.6 MB (PRE-SCALED)
__device__ bf16  g_vt[NH3 * NDIM * VTS];    // [h][d][j'] padded, j-permuted per 64-block
__device__ float g_part[(size_t)NH3 * SEQ * NDIM];  // 100 MB per-head partials (no atomics)
__device__ int   g_isf32;

// ---------------------------------------------------------------- dtype probe
__global__ __launch_bounds__(256) void detect_k(const unsigned short* __restrict__ p) {
    __shared__ int cff, czero;
    if (threadIdx.x == 0) { cff = 0; czero = 0; }
    __syncthreads();
    int ff = 0, zz = 0;
    for (int r = 0; r < 64; ++r) {
        int idx = threadIdx.x * 64 + r;
        unsigned short u = p[idx];
        if (((u >> 7) & 0xFF) == 0xFF) ff++;
        if (((idx & 1) == 0) && (u == 0)) zz++;
    }
    if (ff) atomicAdd(&cff, ff);
    if (zz) atomicAdd(&czero, zz);
    __syncthreads();
    if (threadIdx.x == 0) g_isf32 = (cff > 2 || czero > 6000) ? 1 : 0;
}

// --------------------------------------------------------- input canonicalize
__global__ __launch_bounds__(256) void convert_k(
    const void* s0, const void* s1, const void* s2, const void* s3, const void* s4,
    const void* s5, const void* s6, const void* s7, const void* s8, const void* s9)
{
    const void* srcs[10] = {s0, s1, s2, s3, s4, s5, s6, s7, s8, s9};
    const int   szs[10]  = {524288, 12288, 8192, 524288, 2048, 12288, 2048, 8192, 3145728, 12288};
    const int   offs[10] = {OFF_NODES, OFF_POS, OFF_ROT, OFF_WN, OFF_BN,
                            OFF_WP, OFF_BP, OFF_WR, OFF_WV, OFF_BV};
    const int y = blockIdx.y;
    const void* src = srcs[y];
    bf16* dst = g_in + offs[y];
    const int n = szs[y];
    const int isf = g_isf32;
    const int stride = gridDim.x * 256 * 4;
    for (int i = (blockIdx.x * 256 + threadIdx.x) * 4; i < n; i += stride) {
        bf16x4 o;
        if (isf) {
            float4 v = *(const float4*)((const float*)src + i);
            o[0] = (bf16)v.x; o[1] = (bf16)v.y; o[2] = (bf16)v.z; o[3] = (bf16)v.w;
        } else {
            o = *(const bf16x4*)((const bf16*)src + i);
        }
        *(bf16x4*)(dst + i) = o;
    }
}

// ------------------------------------------------- fused projections (1 launch)
// blocks [0,1024)      : nodes -> k,q heads 0-15   (XCD-swizzled)
// blocks [1024,9216)   : pos/rot -> k,q heads 16-47
// blocks [9216,15360)  : nodes -> V (transposed+permuted), XCD-swizzled
// k,q are PRE-SCALED so the attn P-phase needs no per-element scaling:
//   non-rot heads (0-31): k,q *= 0.5        -> k'q' = kq/4            (= d*0.25)
//   rot heads    (32-47): k,q *= 1/sqrt(2)  -> (k'q')^2 = (kq)^2/4    (= d*d*0.25)
__global__ __launch_bounds__(256) void proj_all()
{
    __shared__ __align__(16) bf16 sB[64 * 264];
    __shared__ __align__(16) bf16 sO[64 * 72];
    const int t  = threadIdx.x;
    const int gb = blockIdx.x;

    if (gb < 1024) {
        // ---------------- nodes -> k,q (heads 0-15)
        const bf16* nodes = g_in + OFF_NODES;
        const bf16* Wn    = g_in + OFF_WN;
        const bf16* bn    = g_in + OFF_BN;
        const int bx   = gb;
        const int xcd  = bx & 7;
        const int rest = bx >> 3;             // 0..127
        const int f0   = (xcd * 4 + (rest & 3)) * 64;   // 4 f-blocks per XCD
        const int s0   = (rest >> 2) * 64;              // 0..31

        for (int rep = 0; rep < 8; ++rep) {
            int idx = t + rep * 256;
            int row = idx >> 5, chunk = idx & 31;
            *(bf16x8*)&sB[row * 264 + chunk * 8] =
                *(const bf16x8*)&Wn[(f0 + row) * 256 + chunk * 8];
        }
        __syncthreads();

        const int w = t >> 6, lane = t & 63;
        const int l15 = lane & 15, quad = lane >> 4;

        f32x4 acc[4] = {{}, {}, {}, {}};
        const bf16* arow = nodes + (s0 + w * 16 + l15) * 256 + quad * 8;
#pragma unroll
        for (int kc = 0; kc < 8; ++kc) {
            bf16x8 af = *(const bf16x8*)(arow + kc * 32);
#pragma unroll
            for (int ft = 0; ft < 4; ++ft) {
                bf16x8 bfr = *(const bf16x8*)&sB[(ft * 16 + l15) * 264 + kc * 32 + quad * 8];
                acc[ft] = __builtin_amdgcn_mfma_f32_16x16x32_bf16(af, bfr, acc[ft], 0, 0, 0);
            }
        }
#pragma unroll
        for (int ft = 0; ft < 4; ++ft) {
            int f = f0 + ft * 16 + l15;
            float bias = (float)bn[f];
            int h = f >> 7, c2 = f & 127;
            bf16* base = (c2 < 64) ? (g_k + h * SEQ * CH + c2)
                                   : (g_q + h * SEQ * CH + (c2 - 64));
#pragma unroll
            for (int r = 0; r < 4; ++r) {
                int s = s0 + w * 16 + quad * 4 + r;
                base[s * CH] = (bf16)((acc[ft][r] + bias) * 0.5f);   // prescale
            }
        }
    } else if (gb < 9216) {
        // ---------------- pos/rot -> k,q (heads 16-31 / 32-47)
        const bf16* pos  = g_in + OFF_POS;
        const bf16* rotq = g_in + OFF_ROT;
        const bf16* Wp   = g_in + OFF_WP;
        const bf16* bp   = g_in + OFF_BP;
        const bf16* Wr   = g_in + OFF_WR;
        int id = (gb - 1024) * 256 + t;           // 2 * 2048 * 512
        int fg  = id & 511;                        // f-group of 4
        int s   = (id >> 9) & 2047;
        int src = id >> 20;
        int f0  = fg * 4;
        float y[4]; int h; float scl;
        if (src == 0) {
#pragma unroll
            for (int j = 0; j < 4; ++j) {
                float a = (float)bp[f0 + j];
#pragma unroll
                for (int x = 0; x < 6; ++x)
                    a += (float)pos[s * 6 + x] * (float)Wp[(f0 + j) * 6 + x];
                y[j] = a;
            }
            h = 16 + (f0 >> 7);
            scl = 0.5f;                          // prescale, non-rot
        } else {
#pragma unroll
            for (int j = 0; j < 4; ++j) {
                float a = 0.f;
#pragma unroll
                for (int x = 0; x < 4; ++x)
                    a += (float)rotq[s * 4 + x] * (float)Wr[(f0 + j) * 4 + x];
                y[j] = a;
            }
            h = 32 + (f0 >> 7);
            scl = 0.70710678f;                   // prescale, rot (1/sqrt2)
        }
        bf16x4 o;
#pragma unroll
        for (int j = 0; j < 4; ++j) o[j] = (bf16)(y[j] * scl);
        int c2 = f0 & 127;
        if (c2 < 64) *(bf16x4*)&g_k[(h * SEQ + s) * CH + c2]        = o;
        else         *(bf16x4*)&g_q[(h * SEQ + s) * CH + (c2 - 64)] = o;
    } else {
        // ---------------- nodes -> V (transposed + j-permuted, padded stride)
        const bf16* nodes = g_in + OFF_NODES;
        const bf16* Wv    = g_in + OFF_WV;
        const bf16* bv    = g_in + OFF_BV;
        const int bx   = gb - 9216;           // 0..6143
        const int xcd  = bx & 7;
        const int rest = bx >> 3;             // 0..767
        const int f0   = (xcd * 24 + (rest % 24)) * 64;  // 24 f-blocks per XCD
        const int s0   = (rest / 24) * 64;               // 0..31

        for (int rep = 0; rep < 8; ++rep) {
            int idx = t + rep * 256;
            int row = idx >> 5, chunk = idx & 31;
            *(bf16x8*)&sB[row * 264 + chunk * 8] =
                *(const bf16x8*)&Wv[(size_t)(f0 + row) * 256 + chunk * 8];
        }
        __syncthreads();

        const int w = t >> 6, lane = t & 63;
        const int l15 = lane & 15, quad = lane >> 4;

        f32x4 acc[4] = {{}, {}, {}, {}};
        const bf16* arow = nodes + (s0 + w * 16 + l15) * 256 + quad * 8;
#pragma unroll
        for (int kc = 0; kc < 8; ++kc) {
            bf16x8 af = *(const bf16x8*)(arow + kc * 32);
#pragma unroll
            for (int ft = 0; ft < 4; ++ft) {
                bf16x8 bfr = *(const bf16x8*)&sB[(ft * 16 + l15) * 264 + kc * 32 + quad * 8];
                acc[ft] = __builtin_amdgcn_mfma_f32_16x16x32_bf16(af, bfr, acc[ft], 0, 0, 0);
            }
        }
        __syncthreads();
#pragma unroll
        for (int ft = 0; ft < 4; ++ft) {
            int n = f0 + ft * 16 + l15;
            float bias = (float)bv[n];
#pragma unroll
            for (int r = 0; r < 4; ++r) {
                // s-local l = w*16+quad*4+r -> j' = (quad*4+r)*4 + w
                sO[(ft * 16 + l15) * 72 + (quad * 4 + r) * 4 + w] = (bf16)(acc[ft][r] + bias);
            }
        }
        __syncthreads();
        for (int rep = 0; rep < 2; ++rep) {
            int idx = t + rep * 256;
            int row = idx >> 3, chunk = idx & 7;
            *(bf16x8*)&g_vt[(size_t)(f0 + row) * VTS + s0 + chunk * 8] =
                *(const bf16x8*)&sO[row * 72 + chunk * 8];
        }
    }
}

// ------------------------------------------------------------- attention
// R21 attn = R11/R17 VERBATIM (194 us measured) except the P-phase scaling
// mul is gone (k,q pre-scaled in proj_all): x = rot ? d*d : d.
// Surviving cost model (9 falsified grafts): per block-step ~4850 cyc/CU =
// LDS 56% (volume at dataflow minimum) + VALU 33% + MFMA 5%, ~44% non-overlap
// that scheduling cannot recover at 16 waves/CU (register-capped).
// Failed grafts (keep away): sV-from-global (R12/R19: latency — LDS staging
// IS the latency-hiding), s_setprio (R13: breaks inter-block lockstep L2
// reuse, FETCH 4x), sP 64+XOR (R14: +38us addressing cost), work stealing
// (R16), issue-early qpre/vpre (R18: scratch spill +371MB), j-split grid
// (R20: occupancy up, perf flat -> occupancy not binding).
__global__ __launch_bounds__(512, 4) void attn_k()
{
    const int bx  = blockIdx.x;
    const int xcd = bx & 7;
    const int sub = bx >> 3;             // 0..95
    const int h   = xcd * 6 + (sub % 6); // 6 heads per XCD
    const int it  = sub / 6;             // 0..15
    const int i0  = it * 128;
    const int t   = threadIdx.x;
    const int w   = t >> 6, lane = t & 63;
    const int l15 = lane & 15, quad = lane >> 4;
    const bool rot = (h >= 32);

    __shared__ __align__(16) bf16 sQ[64 * SQS];      //  9216 B
    __shared__ __align__(16) bf16 sV[256 * SVS];     // 36864 B
    __shared__ __align__(16) bf16 sP[128 * SPS];     // 18432 B
    __shared__ float sL[128];                        //   512 B (total 65024)

    const bf16* kb = g_k  + h * SEQ * CH;
    const bf16* qb = g_q  + h * SEQ * CH;
    const bf16* vb = g_vt + (size_t)h * NDIM * VTS;

    // K fragments: wave w owns S-rows i0 + w*16 .. +16
    bf16x8 kf0 = *(const bf16x8*)&kb[(i0 + w * 16 + l15) * CH + quad * 8];
    bf16x8 kf1 = *(const bf16x8*)&kb[(i0 + w * 16 + l15) * CH + 32 + quad * 8];

    // PV split: i-half ih = w>>2 (64 rows), d-quarter dq = w&3 (64 cols)
    const int ih = w >> 2, dq = w & 3;

    // staging decomposition (16B chunks)
    const int qrow = t >> 3, qch = t & 7;

    f32x4 acc[4][4];
#pragma unroll
    for (int a = 0; a < 4; ++a)
#pragma unroll
        for (int b = 0; b < 4; ++b) acc[a][b] = (f32x4){0.f, 0.f, 0.f, 0.f};
    f32x4 lp = {0.f, 0.f, 0.f, 0.f};

    // prefetch step 0 into regs
    bf16x8 qpre, vpre[4];
    qpre = *(const bf16x8*)&qb[t * 8];
#pragma unroll
    for (int rep = 0; rep < 4; ++rep) {
        int idx = t + rep * 512;
        vpre[rep] = *(const bf16x8*)&vb[(size_t)(idx >> 3) * VTS + (idx & 7) * 8];
    }
    // write step 0 to LDS
    *(bf16x8*)&sQ[qrow * SQS + qch * 8] = qpre;
#pragma unroll
    for (int rep = 0; rep < 4; ++rep) {
        int idx = t + rep * 512;
        *(bf16x8*)&sV[(idx >> 3) * SVS + (idx & 7) * 8] = vpre[rep];
    }
    __syncthreads();                                   // B1 (step 0)

    for (int st = 0; st < 32; ++st) {
        // ---- S phase: 16 i-rows x 64 j per wave
        f32x4 sjb[4];
#pragma unroll
        for (int jb = 0; jb < 4; ++jb) {
            bf16x8 q0 = *(const bf16x8*)&sQ[(jb * 16 + l15) * SQS + quad * 8];
            bf16x8 q1 = *(const bf16x8*)&sQ[(jb * 16 + l15) * SQS + 32 + quad * 8];
            f32x4 sa = {};
            sa = __builtin_amdgcn_mfma_f32_16x16x32_bf16(kf0, q0, sa, 0, 0, 0);
            sa = __builtin_amdgcn_mfma_f32_16x16x32_bf16(kf1, q1, sa, 0, 0, 0);
            sjb[jb] = sa;
        }

        // ---- P phase: exp + pack (scaling folded into k/q at projection)
#pragma unroll
        for (int r = 0; r < 4; ++r) {
            bf16x4 pk;
#pragma unroll
            for (int jb = 0; jb < 4; ++jb) {
                float d = sjb[jb][r];
                float x = rot ? (d * d) : d;
                x = fminf(x, 60.f);
                float p = __expf(x);
                lp[r] += p;
                pk[jb] = (bf16)p;
            }
            *(bf16x4*)&sP[(w * 16 + quad * 4 + r) * SPS + l15 * 4] = pk;
        }
        __syncthreads();                               // B2: sP visible

        // ---- issue next step's global loads (drain at B3, covered by PV)
        if (st < 31) {
            const bf16* qn = qb + (st + 1) * 4096;
            const bf16* vn = vb + (st + 1) * 64;
            qpre = *(const bf16x8*)&qn[t * 8];
#pragma unroll
            for (int rep = 0; rep < 4; ++rep) {
                int idx = t + rep * 512;
                vpre[rep] = *(const bf16x8*)&vn[(size_t)(idx >> 3) * VTS + (idx & 7) * 8];
            }
        }

        // ---- PV phase: wave w owns (ih, dq): 64 i x 64 d
#pragma unroll
        for (int kc = 0; kc < 2; ++kc) {
            bf16x8 ap[4], vf[4];
#pragma unroll
            for (int itr = 0; itr < 4; ++itr)
                ap[itr] = *(const bf16x8*)&sP[(ih * 64 + itr * 16 + l15) * SPS + kc * 32 + quad * 8];
#pragma unroll
            for (int dt = 0; dt < 4; ++dt)
                vf[dt] = *(const bf16x8*)&sV[(dq * 64 + dt * 16 + l15) * SVS + kc * 32 + quad * 8];
#pragma unroll
            for (int itr = 0; itr < 4; ++itr)
#pragma unroll
                for (int dt = 0; dt < 4; ++dt)
                    acc[itr][dt] = __builtin_amdgcn_mfma_f32_16x16x32_bf16(
                        ap[itr], vf[dt], acc[itr][dt], 0, 0, 0);
        }
        __syncthreads();                               // B3: all LDS reads done

        // ---- write staged regs for next step
        if (st < 31) {
            *(bf16x8*)&sQ[qrow * SQS + qch * 8] = qpre;
#pragma unroll
            for (int rep = 0; rep < 4; ++rep) {
                int idx = t + rep * 512;
                *(bf16x8*)&sV[(idx >> 3) * SVS + (idx & 7) * 8] = vpre[rep];
            }
            __syncthreads();                           // B1: staging visible
        }
    }

    // l reduce across the 16 j-lanes (wave w owns S-rows w*16..+16)
#pragma unroll
    for (int off = 1; off < 16; off <<= 1) {
#pragma unroll
        for (int r = 0; r < 4; ++r) lp[r] += __shfl_xor(lp[r], off, 64);
    }
    if (l15 == 0) *(f32x4*)&sL[w * 16 + quad * 4] = lp;
    __syncthreads();

    // normalize + plain stores into this head's private partial plane
    float* pb = g_part + (size_t)h * SEQ * NDIM;
#pragma unroll
    for (int itr = 0; itr < 4; ++itr) {
        f32x4 lv = *(const f32x4*)&sL[ih * 64 + itr * 16 + quad * 4];
#pragma unroll
        for (int r = 0; r < 4; ++r) {
            float inv = 1.0f / lv[r];
            float* ob = &pb[(size_t)(i0 + ih * 64 + itr * 16 + quad * 4 + r) * NDIM + dq * 64 + l15];
#pragma unroll
            for (int dt = 0; dt < 4; ++dt)
                ob[dt * 16] = acc[itr][dt][r] * inv;
        }
    }
}

// ------------------------------------------- finalize: sum 48 head planes
__global__ __launch_bounds__(256) void finalize_k(float* __restrict__ out) {
    int idx = (blockIdx.x * 256 + threadIdx.x) * 4;
    f32x4 s = {0.f, 0.f, 0.f, 0.f};
#pragma unroll
    for (int hh = 0; hh < NH3; ++hh)
        s += *(const f32x4*)&g_part[(size_t)hh * SEQ * NDIM + idx];
    *(f32x4*)&out[idx] = s;
}

extern "C" void kernel_launch(void* const* d_in, const int* in_sizes, int n_in,
                              void* d_out, int out_size, void* d_ws, size_t ws_size,
                              hipStream_t stream) {
    detect_k <<<dim3(1),        dim3(256), 0, stream>>>((const unsigned short*)d_in[8]);
    convert_k<<<dim3(768, 10),  dim3(256), 0, stream>>>(d_in[0], d_in[1], d_in[2], d_in[3],
                                                        d_in[4], d_in[5], d_in[6], d_in[7],
                                                        d_in[8], d_in[9]);
    proj_all  <<<dim3(15360),   dim3(256), 0, stream>>>();
    attn_k    <<<dim3(768),     dim3(512), 0, stream>>>();
    finalize_k<<<dim3(512),     dim3(256), 0, stream>>>((float*)d_out);
}